// Round 8
// baseline (855.016 us; speedup 1.0000x reference)
//
#include <hip/hip_runtime.h>
#include <cstdint>
#include <cstddef>

#define BB  32
#define FF  10
#define NBN 20
#define HH  128
#define GG  5
#define BSTR (FF*NBN*HH)   // 25600
#define FSTR (NBN*HH)      // 2560
#define XPAD 132           // LDS [b][k] row stride (floats)
#define NCELLS 400
#define SC_SYS __HIP_MEMORY_SCOPE_SYSTEM

struct StageList { int cnt; int cells[20]; };  // packed (r<<16)|(f<<8)|n

__device__ __forceinline__ float sigm(float x) {
  return 1.f / (1.f + __expf(-x));
}
__device__ __forceinline__ float tanh_fast(float x) {
  float e = __expf(-2.f * fabsf(x));
  float t = (1.f - e) / (1.f + e);
  return copysignf(t, x);
}
__device__ __forceinline__ void fma4(float4& a, const float4 w, const float h) {
  a.x = fmaf(w.x, h, a.x); a.y = fmaf(w.y, h, a.y);
  a.z = fmaf(w.z, h, a.z); a.w = fmaf(w.w, h, a.w);
}
__device__ __forceinline__ void add4(float4& a, const float4 b) {
  a.x += b.x; a.y += b.y; a.z += b.z; a.w += b.w;
}

// Boundary vectors (pure functions of inputs).
__global__ void precompute_kernel(
    const float* __restrict__ hid, const float* __restrict__ cell,
    const float* __restrict__ gt,
    float* __restrict__ top_c, float* __restrict__ left_c,
    float* __restrict__ top_h0, float* __restrict__ top_h1,
    float* __restrict__ left_h) {
  int idx = blockIdx.x * 256 + threadIdx.x;
  const int NTOP = BB * NBN * HH;
  const int NLEFT = BB * FF * HH;
  if (idx < NTOP) {
    int h = idx & (HH - 1);
    int n = (idx >> 7) % NBN;
    int b = idx / (HH * NBN);
    const float* hp = hid + (size_t)b * BSTR + n * HH + h;
    const float* cp = cell + (size_t)b * BSTR + n * HH + h;
    float sh = 0.f, sc = 0.f;
#pragma unroll
    for (int f = 0; f < FF; ++f) { sh += hp[f * FSTR]; sc += cp[f * FSTR]; }
    top_c[idx]  = sc * (1.f / FF);
    top_h0[idx] = sh * (1.f / FF);
    top_h1[idx] = (sh + gt[idx]) * (1.f / (FF + 1));
  } else if (idx < NTOP + NLEFT) {
    int j = idx - NTOP;
    int h = j & (HH - 1);
    int f = (j >> 7) % FF;
    int b = j / (HH * FF);
    const float* hp = hid + (size_t)b * BSTR + f * FSTR + h;
    const float* cp = cell + (size_t)b * BSTR + f * FSTR + h;
    float sh = 0.f, sc = 0.f;
#pragma unroll
    for (int n = 0; n < NBN; ++n) { sh += hp[n * HH]; sc += cp[n * HH]; }
    left_c[j] = sc * (1.f / NBN);
    left_h[j] = sh * (1.f / NBN);
  }
}

// One wavefront stage, gemv + fused combine. grid = cnt*10 (cell, gate, col-half),
// 256 threads. Unified GEMV both steps:
//   Z = x2.U + ht.Wt + hs.Ws + bias   (r0: x2=p; r1: x2=h0)
// Rendezvous: each slice block fetch_add's zcnt[cell] (ACQ_REL, SYSTEM scope —
// release flushes its Z stores, acquire invalidates for its Z reads); the block
// that sees old==9 runs the gate-combine. NO spin loops anywhere.
__global__ __launch_bounds__(256, 2)
void stage_fused(const float* __restrict__ p,
                 const float* __restrict__ U,
                 const float* __restrict__ Wt,
                 const float* __restrict__ Ws,
                 const float* __restrict__ bias,
                 const float* __restrict__ top_c,
                 const float* __restrict__ left_c,
                 const float* __restrict__ top_h0,
                 const float* __restrict__ top_h1,
                 const float* __restrict__ left_h,
                 float* __restrict__ h0, float* __restrict__ c0,
                 float* __restrict__ out_h, float* __restrict__ out_c,
                 float* __restrict__ Z,
                 int* __restrict__ zcnt,
                 StageList sl) {
  __shared__ __align__(16) float xt[3 * BB * XPAD];  // 50688 B
  __shared__ int s_old;

  const int cellIdx = blockIdx.x / 10;
  const int sub = blockIdx.x % 10;
  const int g = sub >> 1, ch = sub & 1;
  const int packed = sl.cells[cellIdx];
  const int r = (packed >> 16) & 0xff;
  const int f = (packed >> 8) & 0xff;
  const int n = packed & 0xff;
  const int cid = r * 200 + f * NBN + n;
  const int t = threadIdx.x;
  const int cellofs = f * FSTR + n * HH;

  // ---- stage the three x-vectors into LDS [b][k] ----
  const float* hbase = r ? out_h : h0;
  const float* hp; int hbs;
  if (f > 0) { hp = hbase + cellofs - FSTR; hbs = BSTR; }
  else       { hp = (r ? top_h1 : top_h0) + n * HH; hbs = FSTR; }
  const float* lp; int lbs;
  if (n > 0) { lp = hbase + cellofs - HH; lbs = BSTR; }
  else       { lp = left_h + f * HH; lbs = FF * HH; }
  const float* xp = (r ? h0 : p) + cellofs;

  for (int i = t; i < BB * HH; i += 256) {
    int b = i >> 7, k = i & (HH - 1);
    xt[(0 * BB + b) * XPAD + k] = hp[(size_t)b * hbs + k];
    xt[(1 * BB + b) * XPAD + k] = lp[(size_t)b * lbs + k];
    xt[(2 * BB + b) * XPAD + k] = xp[(size_t)b * BSTR + k];
  }
  __syncthreads();

  // ---- GEMV: thread = 4 cols x 8 batches, wave = k-quarter ----
  const int cg = t & 15, bq = (t >> 4) & 3, kh = t >> 6;
  const int col = ch * 64 + cg * 4;
  const size_t wofs = ((size_t)(r * FF + f) * NBN + n) * ((size_t)GG * HH * HH)
                    + (size_t)g * HH * HH + (size_t)(kh * 32) * HH + col;
  const float* wtp = Wt + wofs;
  const float* wsp = Ws + wofs;
  const float* wup = U + wofs;
  const int ka0 = kh * 32;

  float4 acc[8];
#pragma unroll
  for (int i = 0; i < 8; ++i) acc[i] = make_float4(0.f, 0.f, 0.f, 0.f);

  for (int kk = 0; kk < 32; kk += 4) {
    float4 wT[4], wS[4], wU[4];
#pragma unroll
    for (int j = 0; j < 4; ++j) {
      wT[j] = *(const float4*)(wtp + (size_t)(kk + j) * HH);
      wS[j] = *(const float4*)(wsp + (size_t)(kk + j) * HH);
      wU[j] = *(const float4*)(wup + (size_t)(kk + j) * HH);
    }
    const int ka = ka0 + kk;
#pragma unroll
    for (int i = 0; i < 8; ++i) {
      const int b = bq + 4 * i;
      float4 xT = *(const float4*)&xt[(0 * BB + b) * XPAD + ka];
      float4 xS = *(const float4*)&xt[(1 * BB + b) * XPAD + ka];
      float4 xU = *(const float4*)&xt[(2 * BB + b) * XPAD + ka];
      float4 a = acc[i];
      fma4(a, wT[0], xT.x); fma4(a, wT[1], xT.y); fma4(a, wT[2], xT.z); fma4(a, wT[3], xT.w);
      fma4(a, wS[0], xS.x); fma4(a, wS[1], xS.y); fma4(a, wS[2], xS.z); fma4(a, wS[3], xS.w);
      fma4(a, wU[0], xU.x); fma4(a, wU[1], xU.y); fma4(a, wU[2], xU.z); fma4(a, wU[3], xU.w);
      acc[i] = a;
    }
  }

  // ---- k-quarter reduce via LDS, then Z write (overwrite, bias folded in) ----
  __syncthreads();
  const int lane = t & 63;
  if (kh > 0) {
    float* rp = xt + (size_t)((kh - 1) * 64 + lane) * 36;
#pragma unroll
    for (int i = 0; i < 8; ++i) *(float4*)(rp + 4 * i) = acc[i];
  }
  __syncthreads();
  if (kh == 0) {
#pragma unroll
    for (int q = 0; q < 3; ++q) {
      const float* rp = xt + (size_t)(q * 64 + lane) * 36;
#pragma unroll
      for (int i = 0; i < 8; ++i) add4(acc[i], *(const float4*)(rp + 4 * i));
    }
    float4 bv = *(const float4*)(bias + ((size_t)(r * FF + f) * NBN + n) * (GG * HH)
                                      + (size_t)g * HH + col);
    float* zbase = Z + (size_t)(f * NBN + n) * (BB * GG * HH) + (size_t)g * HH + col;
#pragma unroll
    for (int i = 0; i < 8; ++i) {
      add4(acc[i], bv);
      *(float4*)(zbase + (size_t)(bq + 4 * i) * (GG * HH)) = acc[i];
    }
  }
  __syncthreads();  // Z stores issued by wave 0; converge before rendezvous

  // ---- spin-free rendezvous: the 10th finisher runs the combine ----
  if (t == 0)
    s_old = __hip_atomic_fetch_add(&zcnt[cid], 1, __ATOMIC_ACQ_REL, SC_SYS);
  __syncthreads();

  if (s_old == 9) {
    const int c = t & (HH - 1), bh = t >> 7;  // 2 halves x 16 batches
    float* hout = r ? out_h : h0;
    float* cout = r ? out_c : c0;
    const float* ctp; int ctbs;
    if (f > 0) { ctp = cout + cellofs - FSTR; ctbs = BSTR; }
    else       { ctp = top_c + n * HH; ctbs = FSTR; }
    const float* clp; int clbs;
    if (n > 0) { clp = cout + cellofs - HH; clbs = BSTR; }
    else       { clp = left_c + f * HH; clbs = FF * HH; }

    const float* zp = Z + (size_t)(f * NBN + n) * (BB * GG * HH) + c;
#pragma unroll
    for (int j = 0; j < 16; ++j) {
      const int b = bh * 16 + j;
      const float* zb = zp + (size_t)b * (GG * HH);
      float zi = zb[0], zfs = zb[HH], zft = zb[2 * HH], zo = zb[3 * HH], zc = zb[4 * HH];
      float clv = clp[(size_t)b * clbs + c];
      float ctv = ctp[(size_t)b * ctbs + c];
      float iv = sigm(zi), fsv = sigm(zfs), ftv = sigm(zft), ov = sigm(zo);
      float cn = tanh_fast(zc);
      float cnew = fmaf(iv, cn, fmaf(fsv, clv, ftv * ctv));
      float hnew = ov * tanh_fast(cnew);
      hout[(size_t)b * BSTR + cellofs + c] = hnew;
      cout[(size_t)b * BSTR + cellofs + c] = cnew;
    }
  }
}

extern "C" void kernel_launch(void* const* d_in, const int* in_sizes, int n_in,
                              void* d_out, int out_size, void* d_ws, size_t ws_size,
                              hipStream_t stream) {
  const float* hid  = (const float*)d_in[0];
  const float* cell = (const float*)d_in[1];
  const float* gt   = (const float*)d_in[2];
  // d_in[3] = global_s_state — dead for R=2
  const float* p    = (const float*)d_in[4];
  const float* U    = (const float*)d_in[5];
  const float* Wt   = (const float*)d_in[6];
  const float* Ws   = (const float*)d_in[7];
  const float* bias = (const float*)d_in[8];

  float* out_h = (float*)d_out;
  float* out_c = out_h + (size_t)BB * BSTR;

  float* w = (float*)d_ws;
  float* h0     = w; w += (size_t)BB * BSTR;
  float* c0     = w; w += (size_t)BB * BSTR;
  float* top_c  = w; w += (size_t)BB * NBN * HH;
  float* left_c = w; w += (size_t)BB * FF * HH;
  float* top_h0 = w; w += (size_t)BB * NBN * HH;
  float* top_h1 = w; w += (size_t)BB * NBN * HH;
  float* left_h = w; w += (size_t)BB * FF * HH;
  float* Z      = w; w += (size_t)FF * NBN * BB * GG * HH;  // 16.4 MB
  int* zcnt = (int*)w;  // [400]

  // zero rendezvous counters every call (ws not re-poisoned between replays)
  hipMemsetAsync(zcnt, 0, NCELLS * sizeof(int), stream);

  const int pre_threads = BB * NBN * HH + BB * FF * HH;
  hipLaunchKernelGGL(precompute_kernel, dim3((pre_threads + 255) / 256), dim3(256),
                     0, stream, hid, cell, gt, top_c, left_c, top_h0, top_h1, left_h);

  // 30 wavefront stages: r0 cells at d=f+n, r1 cells at d=f+n+1
  for (int d = 0; d < FF + NBN; ++d) {
    StageList sl; sl.cnt = 0;
    for (int r = 0; r < 2; ++r) {
      int dd = d - r;
      for (int f = 0; f < FF; ++f) {
        int n = dd - f;
        if (n >= 0 && n < NBN) sl.cells[sl.cnt++] = (r << 16) | (f << 8) | n;
      }
    }
    if (sl.cnt == 0) continue;
    hipLaunchKernelGGL(stage_fused, dim3(sl.cnt * 10), dim3(256), 0, stream,
                       p, U, Wt, Ws, bias, top_c, left_c, top_h0, top_h1, left_h,
                       h0, c0, out_h, out_c, Z, zcnt, sl);
  }
}